// Round 7
// baseline (900.305 us; speedup 1.0000x reference)
//
#include <hip/hip_runtime.h>
#include <hip/hip_bf16.h>
#include <math.h>

#define F_IN 512
#define H1   16
#define C2   40
#define BKL  6                 // log2(nodes per bucket)
#define BK   (1 << BKL)        // 64 nodes per bucket
#define NBMAX 2048
#define G    1024              // edge-chunk groups for count/fill
#define TPAD 256               // bucket edge-count padding (block stride)

__device__ __forceinline__ float bf2f(unsigned short u) {
  union { unsigned int i; float f; } v; v.i = ((unsigned int)u) << 16; return v.f;
}
__device__ __forceinline__ unsigned short f2bf(float f) {
  __hip_bfloat16 b = __float2bfloat16(f);  // RNE
  return *reinterpret_cast<unsigned short*>(&b);
}

// ---------------- phase 1: per-chunk bucket histogram (LDS atomics only) ----------------
__global__ __launch_bounds__(256) void k_count(const int* __restrict__ dst,
                                               int* __restrict__ cnt,
                                               int E, int NB, int epb) {
  __shared__ int h[NBMAX];
  int g = blockIdx.x, t = threadIdx.x;
  for (int i = t; i < NB; i += 256) h[i] = 0;
  __syncthreads();
  int e0 = g * epb, e1 = min(e0 + epb, E);
  for (int e = e0 + t; e < e1; e += 256) atomicAdd(&h[dst[e] >> BKL], 1);
  __syncthreads();
  for (int i = t; i < NB; i += 256) cnt[g * NB + i] = h[i];
}

// ---------------- phase 2a: per-bucket exclusive scan over the G groups ----------------
__global__ __launch_bounds__(G) void k_scan_col(int* cnt, int* tot, int NB) {
  __shared__ int lds[G];
  int b = blockIdx.x, t = threadIdx.x;
  int v = cnt[t * NB + b];
  lds[t] = v;
  __syncthreads();
  for (int off = 1; off < G; off <<= 1) {
    int add = (t >= off) ? lds[t - off] : 0;
    __syncthreads();
    lds[t] += add;
    __syncthreads();
  }
  cnt[t * NB + b] = lds[t] - v;         // exclusive within bucket
  if (t == G - 1) tot[b] = lds[G - 1];  // bucket total (real edges)
}

// ---------------- phase 2b: exclusive scan of PADDED bucket totals ----------------
__global__ __launch_bounds__(512) void k_scan_tot(const int* __restrict__ tot,
                                                  int* bstart, int NB) {
  __shared__ int lds[512];
  int t = threadIdx.x;
  int b0 = t * 4;
  int v[4];
  int s = 0;
#pragma unroll
  for (int k = 0; k < 4; k++) {
    int tv = (b0 + k < NB) ? tot[b0 + k] : 0;
    v[k] = (tv + TPAD - 1) & ~(TPAD - 1);   // pad to multiple of TPAD
    s += v[k];
  }
  lds[t] = s;
  __syncthreads();
  for (int off = 1; off < 512; off <<= 1) {
    int add = (t >= off) ? lds[t - off] : 0;
    __syncthreads();
    lds[t] += add;
    __syncthreads();
  }
  int excl = lds[t] - s;
#pragma unroll
  for (int k = 0; k < 4; k++) {
    if (b0 + k < NB) bstart[b0 + k] = excl;
    excl += v[k];
  }
  if (t == 511) bstart[NB] = excl;  // padded grand total
}

// ---------------- phase 3: fill (LDS cursors, private sub-ranges, no global atomics) ----------------
__global__ __launch_bounds__(256) void k_fill(const int* __restrict__ src,
                                              const int* __restrict__ dst,
                                              const int* __restrict__ cnt,
                                              const int* __restrict__ bstart,
                                              unsigned* __restrict__ ebuf,
                                              int E, int NB, int epb) {
  __shared__ int cur[NBMAX];
  int g = blockIdx.x, t = threadIdx.x;
  for (int i = t; i < NB; i += 256) cur[i] = bstart[i] + cnt[g * NB + i];
  __syncthreads();
  int e0 = g * epb, e1 = min(e0 + epb, E);
  for (int e = e0 + t; e < e1; e += 256) {
    int d = dst[e];
    int pos = atomicAdd(&cur[d >> BKL], 1);
    ebuf[pos] = ((unsigned)src[e] << BKL) | (unsigned)(d & (BK - 1));
  }
}

// ---------------- phase 4: sentinel-pad each bucket to its padded end ----------------
__global__ __launch_bounds__(128) void k_pad(const int* __restrict__ tot,
                                             const int* __restrict__ bstart,
                                             unsigned* __restrict__ ebuf, int N) {
  int b = blockIdx.x, t = threadIdx.x;
  unsigned SENT = ((unsigned)N) << BKL;   // src = zero-row N, slot 0
  int s = bstart[b] + tot[b], e = bstart[b + 1];
  for (int i = s + t; i < e; i += 128) ebuf[i] = SENT;
}

// ---------------- zero the sentinel message row ----------------
__global__ __launch_bounds__(64) void k_zrow(unsigned short* g1bf, unsigned short* g2bf, int N) {
  int t = threadIdx.x;
  if (t < H1) { g1bf[(size_t)N * H1 + t] = 0; g2bf[(size_t)N * H1 + t] = 0; }
}

// ---------------- per-node degree from grouped ebuf (real range only) -> dinv ----------------
__global__ __launch_bounds__(256) void k_dinv2(const unsigned* __restrict__ ebuf,
                                               const int* __restrict__ bstart,
                                               const int* __restrict__ tot,
                                               float* __restrict__ dinv, int N) {
  __shared__ int c[BK];
  int b = blockIdx.x, t = threadIdx.x;
  if (t < BK) c[t] = 0;
  __syncthreads();
  int e0 = bstart[b], e1 = e0 + tot[b];
  for (int e = e0 + t; e < e1; e += 256) atomicAdd(&c[ebuf[e] & (BK - 1)], 1);
  __syncthreads();
  int node = b * BK + t;
  if (t < BK && node < N) dinv[node] = rsqrtf((float)(c[t] + 1));
}

// ---------------- g1 = bf16( (x @ W1) * dinv[row] ), 2 rows/wave ----------------
__global__ __launch_bounds__(256, 2) void k_gemm1(const float* __restrict__ x,
                                                  const float* __restrict__ W1,
                                                  const float* __restrict__ dinv,
                                                  unsigned short* __restrict__ g1bf, int N) {
  int lane = threadIdx.x & 63;
  int wid = (int)((blockIdx.x * (long long)blockDim.x + threadIdx.x) >> 6);
  int nw = (gridDim.x * blockDim.x) >> 6;

  float wr[128];
#pragma unroll
  for (int j = 0; j < 8; j++) {
    const float* wrow = &W1[(lane * 8 + j) * H1];
    float4 w0 = *(const float4*)&wrow[0];
    float4 w1 = *(const float4*)&wrow[4];
    float4 w2 = *(const float4*)&wrow[8];
    float4 w3 = *(const float4*)&wrow[12];
    wr[j*16+ 0]=w0.x; wr[j*16+ 1]=w0.y; wr[j*16+ 2]=w0.z; wr[j*16+ 3]=w0.w;
    wr[j*16+ 4]=w1.x; wr[j*16+ 5]=w1.y; wr[j*16+ 6]=w1.z; wr[j*16+ 7]=w1.w;
    wr[j*16+ 8]=w2.x; wr[j*16+ 9]=w2.y; wr[j*16+10]=w2.z; wr[j*16+11]=w2.w;
    wr[j*16+12]=w3.x; wr[j*16+13]=w3.y; wr[j*16+14]=w3.z; wr[j*16+15]=w3.w;
  }

  int row = wid * 2;
  int step = nw * 2;
  float4 A0 = make_float4(0,0,0,0), A1 = A0, B0 = A0, B1 = A0;
  if (row < N) {
    const float4* xr = (const float4*)(x + (size_t)row * F_IN);
    A0 = xr[lane * 2]; A1 = xr[lane * 2 + 1];
    if (row + 1 < N) {
      const float4* xr2 = (const float4*)(x + (size_t)(row + 1) * F_IN);
      B0 = xr2[lane * 2]; B1 = xr2[lane * 2 + 1];
    }
  }
  while (row < N) {
    int nrow = row + step;
    float4 nA0 = make_float4(0,0,0,0), nA1 = nA0, nB0 = nA0, nB1 = nA0;
    if (nrow < N) {
      const float4* xr = (const float4*)(x + (size_t)nrow * F_IN);
      nA0 = xr[lane * 2]; nA1 = xr[lane * 2 + 1];
      if (nrow + 1 < N) {
        const float4* xr2 = (const float4*)(x + (size_t)(nrow + 1) * F_IN);
        nB0 = xr2[lane * 2]; nB1 = xr2[lane * 2 + 1];
      }
    }
    float xa[8] = {A0.x, A0.y, A0.z, A0.w, A1.x, A1.y, A1.z, A1.w};
    float xb[8] = {B0.x, B0.y, B0.z, B0.w, B1.x, B1.y, B1.z, B1.w};
    float accA[16], accB[16];
#pragma unroll
    for (int c = 0; c < 16; c++) { accA[c] = 0.f; accB[c] = 0.f; }
#pragma unroll
    for (int j = 0; j < 8; j++)
#pragma unroll
      for (int c = 0; c < 16; c++) {
        accA[c] = fmaf(xa[j], wr[j * 16 + c], accA[c]);
        accB[c] = fmaf(xb[j], wr[j * 16 + c], accB[c]);
      }

    float a8[8], b8[8];
#pragma unroll
    for (int i = 0; i < 8; i++) {
      float t0 = accA[2*i]   + __shfl_xor(accA[2*i],   1, 64);
      float t1 = accA[2*i+1] + __shfl_xor(accA[2*i+1], 1, 64);
      a8[i] = (lane & 1) ? t1 : t0;
      float s0 = accB[2*i]   + __shfl_xor(accB[2*i],   1, 64);
      float s1 = accB[2*i+1] + __shfl_xor(accB[2*i+1], 1, 64);
      b8[i] = (lane & 1) ? s1 : s0;
    }
    float a4[4], b4[4];
#pragma unroll
    for (int i = 0; i < 4; i++) {
      float t0 = a8[2*i]   + __shfl_xor(a8[2*i],   2, 64);
      float t1 = a8[2*i+1] + __shfl_xor(a8[2*i+1], 2, 64);
      a4[i] = ((lane >> 1) & 1) ? t1 : t0;
      float s0 = b8[2*i]   + __shfl_xor(b8[2*i],   2, 64);
      float s1 = b8[2*i+1] + __shfl_xor(b8[2*i+1], 2, 64);
      b4[i] = ((lane >> 1) & 1) ? s1 : s0;
    }
    float a2[2], b2v[2];
#pragma unroll
    for (int i = 0; i < 2; i++) {
      float t0 = a4[2*i]   + __shfl_xor(a4[2*i],   4, 64);
      float t1 = a4[2*i+1] + __shfl_xor(a4[2*i+1], 4, 64);
      a2[i] = ((lane >> 2) & 1) ? t1 : t0;
      float s0 = b4[2*i]   + __shfl_xor(b4[2*i],   4, 64);
      float s1 = b4[2*i+1] + __shfl_xor(b4[2*i+1], 4, 64);
      b2v[i] = ((lane >> 2) & 1) ? s1 : s0;
    }
    float ta0 = a2[0] + __shfl_xor(a2[0], 8, 64);
    float ta1 = a2[1] + __shfl_xor(a2[1], 8, 64);
    float va = ((lane >> 3) & 1) ? ta1 : ta0;
    float tb0 = b2v[0] + __shfl_xor(b2v[0], 8, 64);
    float tb1 = b2v[1] + __shfl_xor(b2v[1], 8, 64);
    float vb = ((lane >> 3) & 1) ? tb1 : tb0;
    va += __shfl_xor(va, 16, 64); va += __shfl_xor(va, 32, 64);
    vb += __shfl_xor(vb, 16, 64); vb += __shfl_xor(vb, 32, 64);

    if (lane < 16) {
      g1bf[(size_t)row * H1 + lane] = f2bf(va * dinv[row]);
      if (row + 1 < N) g1bf[(size_t)(row + 1) * H1 + lane] = f2bf(vb * dinv[row + 1]);
    }
    row = nrow; A0 = nA0; A1 = nA1; B0 = nB0; B1 = nB1;
  }
}

// ---------------- layer-1 aggregate: edge-per-lane, uint4 row gather ----------------
// Lane owns one edge: coalesced ebuf read, 2x uint4 gather of the 32B message
// row, 16 LDS atomicAdds. Swizzle j -> (j + (slot>>1)) & 15 spreads each
// fixed-j atomic instruction across all 32 banks at <=2-way.
__global__ __launch_bounds__(256) void k_agg1(const unsigned* __restrict__ ebuf,
                                              const int* __restrict__ bstart,
                                              const unsigned short* __restrict__ g1bf,
                                              const float* __restrict__ dinv,
                                              const float* __restrict__ b1,
                                              unsigned short* __restrict__ g2bf, int N) {
  __shared__ float acc[BK * H1];  // 4 KB
  int t = threadIdx.x;
  int bb = blockIdx.x;
  for (int i = t; i < BK * H1; i += 256) acc[i] = 0.f;
  __syncthreads();

  int e0 = bstart[bb], e1 = bstart[bb + 1];  // (e1-e0) % TPAD == 0
  for (int e = e0 + t; e < e1; e += 256) {
    unsigned p = ebuf[e];
    int slot = p & (BK - 1);
    int sw = slot >> 1;
    const uint4* row = (const uint4*)(g1bf + (size_t)(p >> BKL) * H1);
    uint4 r0 = row[0];
    uint4 r1 = row[1];
    float* a = acc + slot * H1;
    const unsigned* w0 = (const unsigned*)&r0;
    const unsigned* w1 = (const unsigned*)&r1;
#pragma unroll
    for (int k = 0; k < 4; k++) {
      atomicAdd(&a[(2*k     + sw) & 15], bf2f((unsigned short)(w0[k] & 0xffffu)));
      atomicAdd(&a[(2*k + 1 + sw) & 15], bf2f((unsigned short)(w0[k] >> 16)));
      atomicAdd(&a[(2*k + 8 + sw) & 15], bf2f((unsigned short)(w1[k] & 0xffffu)));
      atomicAdd(&a[(2*k + 9 + sw) & 15], bf2f((unsigned short)(w1[k] >> 16)));
    }
  }
  __syncthreads();

  if (t < BK * 2) {
    int nl = t >> 1, half = (t & 1) * 8;
    int node = bb * BK + nl;
    if (node < N) {
      float di = dinv[node];
      int sw = nl >> 1;
      unsigned* dst32 = (unsigned*)g2bf + (size_t)node * (H1 / 2) + (half >> 1);
#pragma unroll
      for (int k = 0; k < 4; k++) {
        int jj = half + 2 * k;
        float v0 = di * (acc[nl * H1 + ((jj     + sw) & 15)] + bf2f(g1bf[(size_t)node * H1 + jj]))     + b1[jj];
        float v1 = di * (acc[nl * H1 + ((jj + 1 + sw) & 15)] + bf2f(g1bf[(size_t)node * H1 + jj + 1])) + b1[jj + 1];
        v0 = fmaxf(v0, 0.f) * di;
        v1 = fmaxf(v1, 0.f) * di;
        dst32[k] = (unsigned)f2bf(v0) | ((unsigned)f2bf(v1) << 16);
      }
    }
  }
}

// ---------------- layer-2 aggregate: edge-per-lane -> s2 fp32 ----------------
__global__ __launch_bounds__(256) void k_agg2(const unsigned* __restrict__ ebuf,
                                              const int* __restrict__ bstart,
                                              const unsigned short* __restrict__ g2bf,
                                              const float* __restrict__ dinv,
                                              float* __restrict__ s2, int N) {
  __shared__ float acc[BK * H1];  // 4 KB
  int t = threadIdx.x;
  int bb = blockIdx.x;
  for (int i = t; i < BK * H1; i += 256) acc[i] = 0.f;
  __syncthreads();

  int e0 = bstart[bb], e1 = bstart[bb + 1];
  for (int e = e0 + t; e < e1; e += 256) {
    unsigned p = ebuf[e];
    int slot = p & (BK - 1);
    int sw = slot >> 1;
    const uint4* row = (const uint4*)(g2bf + (size_t)(p >> BKL) * H1);
    uint4 r0 = row[0];
    uint4 r1 = row[1];
    float* a = acc + slot * H1;
    const unsigned* w0 = (const unsigned*)&r0;
    const unsigned* w1 = (const unsigned*)&r1;
#pragma unroll
    for (int k = 0; k < 4; k++) {
      atomicAdd(&a[(2*k     + sw) & 15], bf2f((unsigned short)(w0[k] & 0xffffu)));
      atomicAdd(&a[(2*k + 1 + sw) & 15], bf2f((unsigned short)(w0[k] >> 16)));
      atomicAdd(&a[(2*k + 8 + sw) & 15], bf2f((unsigned short)(w1[k] & 0xffffu)));
      atomicAdd(&a[(2*k + 9 + sw) & 15], bf2f((unsigned short)(w1[k] >> 16)));
    }
  }
  __syncthreads();

  if (t < BK * 2) {
    int nl = t >> 1, half = (t & 1) * 8;
    int node = bb * BK + nl;
    if (node < N) {
      float di = dinv[node];
      int sw = nl >> 1;
#pragma unroll
      for (int k = 0; k < 8; k++) {
        int jj = half + k;
        s2[(size_t)node * H1 + jj] =
            di * (acc[nl * H1 + ((jj + sw) & 15)] + bf2f(g2bf[(size_t)node * H1 + jj]));
      }
    }
  }
}

// ---------------- final epilogue: out = log_softmax(s2 @ W2 + b2) ----------------
__global__ __launch_bounds__(256) void k_ep2(const float* __restrict__ s2,
                                             const float* __restrict__ W2,
                                             const float* __restrict__ b2,
                                             float* __restrict__ out, int N) {
  __shared__ float w2s[H1 * C2];
  __shared__ float b2s[C2];
  int t = threadIdx.x;
  for (int i = t; i < H1 * C2; i += 256) w2s[i] = W2[i];
  if (t < C2) b2s[t] = b2[t];
  __syncthreads();

  int lane = t & 63;
  int node = (int)((blockIdx.x * (long long)blockDim.x + t) >> 6);
  if (node >= N) return;
  float sv = (lane < H1) ? s2[(size_t)node * H1 + lane] : 0.f;
  int cl = (lane < C2) ? lane : 0;
  float z = b2s[cl];
#pragma unroll
  for (int jj = 0; jj < H1; jj++) {
    float sj = __shfl(sv, jj, 64);
    z = fmaf(sj, w2s[jj * C2 + cl], z);
  }
  if (lane >= C2) z = -INFINITY;
  float m = z;
#pragma unroll
  for (int off = 32; off; off >>= 1) m = fmaxf(m, __shfl_xor(m, off, 64));
  float p = (lane < C2) ? expf(z - m) : 0.f;
  float ssum = p;
#pragma unroll
  for (int off = 32; off; off >>= 1) ssum += __shfl_xor(ssum, off, 64);
  if (lane < C2) out[(size_t)node * C2 + lane] = z - m - logf(ssum);
}

extern "C" void kernel_launch(void* const* d_in, const int* in_sizes, int n_in,
                              void* d_out, int out_size, void* d_ws, size_t ws_size,
                              hipStream_t stream) {
  const float* x  = (const float*)d_in[0];
  const int*   ei = (const int*)d_in[1];
  const float* W1 = (const float*)d_in[2];
  const float* b1 = (const float*)d_in[3];
  const float* W2 = (const float*)d_in[4];
  const float* b2 = (const float*)d_in[5];
  float* out = (float*)d_out;

  int N = in_sizes[0] / F_IN;
  int E = in_sizes[1] / 2;
  const int* src = ei;
  const int* dst = ei + E;
  int NB = (N + BK - 1) / BK;     // 1563 for N=100000 (must be <= NBMAX)
  int epb = (E + G - 1) / G;      // edges per chunk group

  char* w = (char*)d_ws;
  size_t off = 0;
  auto alloc = [&](size_t bytes) { char* p = w + off; off = (off + bytes + 255) & ~(size_t)255; return p; };
  int*   cnt    = (int*)alloc((size_t)G * NB * 4);
  int*   tot    = (int*)alloc((size_t)NB * 4);
  int*   bstart = (int*)alloc((size_t)(NB + 1) * 4);
  float* dinv   = (float*)alloc((size_t)N * 4);
  unsigned* ebuf = (unsigned*)alloc(((size_t)E + (size_t)NB * TPAD) * 4);
  unsigned short* g1bf = (unsigned short*)alloc((size_t)(N + 1) * H1 * 2);
  unsigned short* g2bf = (unsigned short*)alloc((size_t)(N + 1) * H1 * 2);
  float* s2 = (float*)cnt;  // alias: cnt dead after k_fill; N*16*4 <= G*NB*4

  k_count   <<<G, 256, 0, stream>>>(dst, cnt, E, NB, epb);
  k_scan_col<<<NB, G, 0, stream>>>(cnt, tot, NB);
  k_scan_tot<<<1, 512, 0, stream>>>(tot, bstart, NB);
  k_fill    <<<G, 256, 0, stream>>>(src, dst, cnt, bstart, ebuf, E, NB, epb);
  k_pad     <<<NB, 128, 0, stream>>>(tot, bstart, ebuf, N);
  k_dinv2   <<<NB, 256, 0, stream>>>(ebuf, bstart, tot, dinv, N);
  k_zrow    <<<1, 64, 0, stream>>>(g1bf, g2bf, N);
  k_gemm1   <<<1024, 256, 0, stream>>>(x, W1, dinv, g1bf, N);
  k_agg1    <<<NB, 256, 0, stream>>>(ebuf, bstart, g1bf, dinv, b1, g2bf, N);
  k_agg2    <<<NB, 256, 0, stream>>>(ebuf, bstart, g2bf, dinv, s2, N);
  k_ep2     <<<(N * 64 + 255) / 256, 256, 0, stream>>>(s2, W2, b2, out, N);
}

// Round 8
// 308.275 us; speedup vs baseline: 2.9205x; 2.9205x over previous
//
#include <hip/hip_runtime.h>
#include <hip/hip_bf16.h>
#include <math.h>

#define F_IN 512
#define H1   16
#define C2   40
#define BKL  6                 // log2(nodes per bucket)
#define BK   (1 << BKL)        // 64 nodes per bucket
#define NBMAX 2048
#define G    1024              // edge-chunk groups for count/fill
#define TPAD 64                // bucket edge-count padding (alignment only)

__device__ __forceinline__ float bf2f(unsigned short u) {
  union { unsigned int i; float f; } v; v.i = ((unsigned int)u) << 16; return v.f;
}
__device__ __forceinline__ unsigned short f2bf(float f) {
  __hip_bfloat16 b = __float2bfloat16(f);  // RNE
  return *reinterpret_cast<unsigned short*>(&b);
}
__device__ __forceinline__ float lo16(unsigned u) { return bf2f((unsigned short)(u & 0xffffu)); }
__device__ __forceinline__ float hi16(unsigned u) { return bf2f((unsigned short)(u >> 16)); }

// ---------------- phase 1: per-chunk bucket histogram (LDS atomics only) ----------------
__global__ __launch_bounds__(256) void k_count(const int* __restrict__ dst,
                                               int* __restrict__ cnt,
                                               int E, int NB, int epb) {
  __shared__ int h[NBMAX];
  int g = blockIdx.x, t = threadIdx.x;
  for (int i = t; i < NB; i += 256) h[i] = 0;
  __syncthreads();
  int e0 = g * epb, e1 = min(e0 + epb, E);
  for (int e = e0 + t; e < e1; e += 256) atomicAdd(&h[dst[e] >> BKL], 1);
  __syncthreads();
  for (int i = t; i < NB; i += 256) cnt[g * NB + i] = h[i];
}

// ---------------- phase 2a: per-bucket exclusive scan over the G groups ----------------
__global__ __launch_bounds__(G) void k_scan_col(int* cnt, int* tot, int NB) {
  __shared__ int lds[G];
  int b = blockIdx.x, t = threadIdx.x;
  int v = cnt[t * NB + b];
  lds[t] = v;
  __syncthreads();
  for (int off = 1; off < G; off <<= 1) {
    int add = (t >= off) ? lds[t - off] : 0;
    __syncthreads();
    lds[t] += add;
    __syncthreads();
  }
  cnt[t * NB + b] = lds[t] - v;         // exclusive within bucket
  if (t == G - 1) tot[b] = lds[G - 1];  // bucket total (real edges)
}

// ---------------- phase 2b: exclusive scan of (aligned) bucket totals ----------------
__global__ __launch_bounds__(512) void k_scan_tot(const int* __restrict__ tot,
                                                  int* bstart, int NB) {
  __shared__ int lds[512];
  int t = threadIdx.x;
  int b0 = t * 4;
  int v[4];
  int s = 0;
#pragma unroll
  for (int k = 0; k < 4; k++) {
    int tv = (b0 + k < NB) ? tot[b0 + k] : 0;
    v[k] = (tv + TPAD - 1) & ~(TPAD - 1);   // pad to multiple of TPAD (alignment)
    s += v[k];
  }
  lds[t] = s;
  __syncthreads();
  for (int off = 1; off < 512; off <<= 1) {
    int add = (t >= off) ? lds[t - off] : 0;
    __syncthreads();
    lds[t] += add;
    __syncthreads();
  }
  int excl = lds[t] - s;
#pragma unroll
  for (int k = 0; k < 4; k++) {
    if (b0 + k < NB) bstart[b0 + k] = excl;
    excl += v[k];
  }
  if (t == 511) bstart[NB] = excl;
}

// ---------------- phase 3: fill (LDS cursors, private sub-ranges, no global atomics) ----------------
__global__ __launch_bounds__(256) void k_fill(const int* __restrict__ src,
                                              const int* __restrict__ dst,
                                              const int* __restrict__ cnt,
                                              const int* __restrict__ bstart,
                                              unsigned* __restrict__ ebuf,
                                              int E, int NB, int epb) {
  __shared__ int cur[NBMAX];
  int g = blockIdx.x, t = threadIdx.x;
  for (int i = t; i < NB; i += 256) cur[i] = bstart[i] + cnt[g * NB + i];
  __syncthreads();
  int e0 = g * epb, e1 = min(e0 + epb, E);
  for (int e = e0 + t; e < e1; e += 256) {
    int d = dst[e];
    int pos = atomicAdd(&cur[d >> BKL], 1);
    ebuf[pos] = ((unsigned)src[e] << BKL) | (unsigned)(d & (BK - 1));
  }
}

// ---------------- phase 4: per-bucket counting sort by dst slot ----------------
// One block per bucket. Per-wave sub-histograms (low contention), wave-0
// shuffle scan, per-wave cursors -> srt[] holds src ids grouped by dst node.
// Also emits per-node count/start and dinv. 2 LDS atomics per edge, total.
__global__ __launch_bounds__(256) void k_sort(const unsigned* __restrict__ ebuf,
                                              const int* __restrict__ bstart,
                                              const int* __restrict__ tot,
                                              int* __restrict__ srt,
                                              int* __restrict__ sstart,
                                              int* __restrict__ scnt,
                                              float* __restrict__ dinv, int N) {
  __shared__ int h[4][BK];
  __shared__ int cur[4][BK];
  __shared__ int stmp[BK];
  int b = blockIdx.x, t = threadIdx.x;
  int w = t >> 6;
  if (t < BK) { h[0][t] = 0; h[1][t] = 0; h[2][t] = 0; h[3][t] = 0; }
  __syncthreads();
  int e0 = bstart[b], e1 = e0 + tot[b];
  for (int e = e0 + t; e < e1; e += 256)
    atomicAdd(&h[w][ebuf[e] & (BK - 1)], 1);
  __syncthreads();
  if (t < BK) stmp[t] = h[0][t] + h[1][t] + h[2][t] + h[3][t];
  __syncthreads();
  if (t < BK) {  // wave 0 exactly: shuffle inclusive scan over 64 slots
    int v = stmp[t];
    int inc = v;
#pragma unroll
    for (int off = 1; off < 64; off <<= 1) {
      int n = __shfl_up(inc, off, 64);
      if (t >= off) inc += n;
    }
    int excl = inc - v;
    scnt[b * BK + t] = v;
    sstart[b * BK + t] = e0 + excl;
    int node = b * BK + t;
    if (node < N) dinv[node] = rsqrtf((float)(v + 1));
    int base = excl;
    cur[0][t] = base; base += h[0][t];
    cur[1][t] = base; base += h[1][t];
    cur[2][t] = base; base += h[2][t];
    cur[3][t] = base;
  }
  __syncthreads();
  for (int e = e0 + t; e < e1; e += 256) {
    unsigned p = ebuf[e];
    int pos = atomicAdd(&cur[w][p & (BK - 1)], 1);
    srt[e0 + pos] = (int)(p >> BKL);
  }
}

// ---------------- g1 = bf16( (x @ W1) * dinv[row] ), 2 rows/wave ----------------
__global__ __launch_bounds__(256, 2) void k_gemm1(const float* __restrict__ x,
                                                  const float* __restrict__ W1,
                                                  const float* __restrict__ dinv,
                                                  unsigned short* __restrict__ g1bf, int N) {
  int lane = threadIdx.x & 63;
  int wid = (int)((blockIdx.x * (long long)blockDim.x + threadIdx.x) >> 6);
  int nw = (gridDim.x * blockDim.x) >> 6;

  float wr[128];
#pragma unroll
  for (int j = 0; j < 8; j++) {
    const float* wrow = &W1[(lane * 8 + j) * H1];
    float4 w0 = *(const float4*)&wrow[0];
    float4 w1 = *(const float4*)&wrow[4];
    float4 w2 = *(const float4*)&wrow[8];
    float4 w3 = *(const float4*)&wrow[12];
    wr[j*16+ 0]=w0.x; wr[j*16+ 1]=w0.y; wr[j*16+ 2]=w0.z; wr[j*16+ 3]=w0.w;
    wr[j*16+ 4]=w1.x; wr[j*16+ 5]=w1.y; wr[j*16+ 6]=w1.z; wr[j*16+ 7]=w1.w;
    wr[j*16+ 8]=w2.x; wr[j*16+ 9]=w2.y; wr[j*16+10]=w2.z; wr[j*16+11]=w2.w;
    wr[j*16+12]=w3.x; wr[j*16+13]=w3.y; wr[j*16+14]=w3.z; wr[j*16+15]=w3.w;
  }

  int row = wid * 2;
  int step = nw * 2;
  float4 A0 = make_float4(0,0,0,0), A1 = A0, B0 = A0, B1 = A0;
  if (row < N) {
    const float4* xr = (const float4*)(x + (size_t)row * F_IN);
    A0 = xr[lane * 2]; A1 = xr[lane * 2 + 1];
    if (row + 1 < N) {
      const float4* xr2 = (const float4*)(x + (size_t)(row + 1) * F_IN);
      B0 = xr2[lane * 2]; B1 = xr2[lane * 2 + 1];
    }
  }
  while (row < N) {
    int nrow = row + step;
    float4 nA0 = make_float4(0,0,0,0), nA1 = nA0, nB0 = nA0, nB1 = nA0;
    if (nrow < N) {
      const float4* xr = (const float4*)(x + (size_t)nrow * F_IN);
      nA0 = xr[lane * 2]; nA1 = xr[lane * 2 + 1];
      if (nrow + 1 < N) {
        const float4* xr2 = (const float4*)(x + (size_t)(nrow + 1) * F_IN);
        nB0 = xr2[lane * 2]; nB1 = xr2[lane * 2 + 1];
      }
    }
    float xa[8] = {A0.x, A0.y, A0.z, A0.w, A1.x, A1.y, A1.z, A1.w};
    float xb[8] = {B0.x, B0.y, B0.z, B0.w, B1.x, B1.y, B1.z, B1.w};
    float accA[16], accB[16];
#pragma unroll
    for (int c = 0; c < 16; c++) { accA[c] = 0.f; accB[c] = 0.f; }
#pragma unroll
    for (int j = 0; j < 8; j++)
#pragma unroll
      for (int c = 0; c < 16; c++) {
        accA[c] = fmaf(xa[j], wr[j * 16 + c], accA[c]);
        accB[c] = fmaf(xb[j], wr[j * 16 + c], accB[c]);
      }

    float a8[8], b8[8];
#pragma unroll
    for (int i = 0; i < 8; i++) {
      float t0 = accA[2*i]   + __shfl_xor(accA[2*i],   1, 64);
      float t1 = accA[2*i+1] + __shfl_xor(accA[2*i+1], 1, 64);
      a8[i] = (lane & 1) ? t1 : t0;
      float s0 = accB[2*i]   + __shfl_xor(accB[2*i],   1, 64);
      float s1 = accB[2*i+1] + __shfl_xor(accB[2*i+1], 1, 64);
      b8[i] = (lane & 1) ? s1 : s0;
    }
    float a4[4], b4[4];
#pragma unroll
    for (int i = 0; i < 4; i++) {
      float t0 = a8[2*i]   + __shfl_xor(a8[2*i],   2, 64);
      float t1 = a8[2*i+1] + __shfl_xor(a8[2*i+1], 2, 64);
      a4[i] = ((lane >> 1) & 1) ? t1 : t0;
      float s0 = b8[2*i]   + __shfl_xor(b8[2*i],   2, 64);
      float s1 = b8[2*i+1] + __shfl_xor(b8[2*i+1], 2, 64);
      b4[i] = ((lane >> 1) & 1) ? s1 : s0;
    }
    float a2[2], b2v[2];
#pragma unroll
    for (int i = 0; i < 2; i++) {
      float t0 = a4[2*i]   + __shfl_xor(a4[2*i],   4, 64);
      float t1 = a4[2*i+1] + __shfl_xor(a4[2*i+1], 4, 64);
      a2[i] = ((lane >> 2) & 1) ? t1 : t0;
      float s0 = b4[2*i]   + __shfl_xor(b4[2*i],   4, 64);
      float s1 = b4[2*i+1] + __shfl_xor(b4[2*i+1], 4, 64);
      b2v[i] = ((lane >> 2) & 1) ? s1 : s0;
    }
    float ta0 = a2[0] + __shfl_xor(a2[0], 8, 64);
    float ta1 = a2[1] + __shfl_xor(a2[1], 8, 64);
    float va = ((lane >> 3) & 1) ? ta1 : ta0;
    float tb0 = b2v[0] + __shfl_xor(b2v[0], 8, 64);
    float tb1 = b2v[1] + __shfl_xor(b2v[1], 8, 64);
    float vb = ((lane >> 3) & 1) ? tb1 : tb0;
    va += __shfl_xor(va, 16, 64); va += __shfl_xor(va, 32, 64);
    vb += __shfl_xor(vb, 16, 64); vb += __shfl_xor(vb, 32, 64);

    if (lane < 16) {
      g1bf[(size_t)row * H1 + lane] = f2bf(va * dinv[row]);
      if (row + 1 < N) g1bf[(size_t)(row + 1) * H1 + lane] = f2bf(vb * dinv[row + 1]);
    }
    row = nrow; A0 = nA0; A1 = nA1; B0 = nB0; B1 = nB1;
  }
}

// ---------------- layer-1 aggregate: LDS-free, 4 lanes/node, register acc ----------------
__global__ __launch_bounds__(256) void k_agg1(const int* __restrict__ srt,
                                              const int* __restrict__ sstart,
                                              const int* __restrict__ scnt,
                                              const unsigned short* __restrict__ g1bf,
                                              const float* __restrict__ dinv,
                                              const float* __restrict__ b1,
                                              unsigned short* __restrict__ g2bf, int N) {
  int t = threadIdx.x, bb = blockIdx.x;
  int slot = t >> 2, L = t & 3;
  int node = bb * BK + slot;
  if (node >= N) return;  // no __syncthreads in this kernel
  int s0 = sstart[bb * BK + slot];
  int end = s0 + scnt[bb * BK + slot];

  float acc[16];
#pragma unroll
  for (int k = 0; k < 16; k++) acc[k] = 0.f;

  // 2-deep software pipeline, named registers
  int e = s0 + L;
  uint4 r0 = make_uint4(0,0,0,0), r1 = r0;
  if (e < end) {
    const uint4* row = (const uint4*)(g1bf + (size_t)srt[e] * H1);
    r0 = row[0]; r1 = row[1];
  }
  while (e < end) {
    int en = e + 4;
    uint4 n0 = make_uint4(0,0,0,0), n1 = n0;
    if (en < end) {
      const uint4* row = (const uint4*)(g1bf + (size_t)srt[en] * H1);
      n0 = row[0]; n1 = row[1];
    }
    acc[0]+=lo16(r0.x); acc[1]+=hi16(r0.x); acc[2]+=lo16(r0.y); acc[3]+=hi16(r0.y);
    acc[4]+=lo16(r0.z); acc[5]+=hi16(r0.z); acc[6]+=lo16(r0.w); acc[7]+=hi16(r0.w);
    acc[8]+=lo16(r1.x); acc[9]+=hi16(r1.x); acc[10]+=lo16(r1.y); acc[11]+=hi16(r1.y);
    acc[12]+=lo16(r1.z); acc[13]+=hi16(r1.z); acc[14]+=lo16(r1.w); acc[15]+=hi16(r1.w);
    r0 = n0; r1 = n1; e = en;
  }

  // reduce-scatter across the 4-lane group: lane keeps 4 features
  float r8[8];
#pragma unroll
  for (int k = 0; k < 8; k++) {
    float a = acc[k]     + __shfl_xor(acc[k],     1, 64);
    float b = acc[8 + k] + __shfl_xor(acc[8 + k], 1, 64);
    r8[k] = (L & 1) ? b : a;
  }
  float r4[4];
#pragma unroll
  for (int k = 0; k < 4; k++) {
    float a = r8[k]     + __shfl_xor(r8[k],     2, 64);
    float b = r8[4 + k] + __shfl_xor(r8[4 + k], 2, 64);
    r4[k] = (L & 2) ? b : a;
  }
  int fb = (L & 1) * 8 + (L & 2) * 2;  // feature base: L0->0 L1->8 L2->4 L3->12

  float di = dinv[node];
  uint2 sf = *(const uint2*)(g1bf + (size_t)node * H1 + fb);
  float4 bv = *(const float4*)(b1 + fb);
  float v0 = fmaxf(di * (r4[0] + lo16(sf.x)) + bv.x, 0.f) * di;
  float v1 = fmaxf(di * (r4[1] + hi16(sf.x)) + bv.y, 0.f) * di;
  float v2 = fmaxf(di * (r4[2] + lo16(sf.y)) + bv.z, 0.f) * di;
  float v3 = fmaxf(di * (r4[3] + hi16(sf.y)) + bv.w, 0.f) * di;
  uint2 out;
  out.x = (unsigned)f2bf(v0) | ((unsigned)f2bf(v1) << 16);
  out.y = (unsigned)f2bf(v2) | ((unsigned)f2bf(v3) << 16);
  *(uint2*)(g2bf + (size_t)node * H1 + fb) = out;
}

// ---------------- layer-2 aggregate: LDS-free -> s2 fp32 ----------------
__global__ __launch_bounds__(256) void k_agg2(const int* __restrict__ srt,
                                              const int* __restrict__ sstart,
                                              const int* __restrict__ scnt,
                                              const unsigned short* __restrict__ g2bf,
                                              const float* __restrict__ dinv,
                                              float* __restrict__ s2, int N) {
  int t = threadIdx.x, bb = blockIdx.x;
  int slot = t >> 2, L = t & 3;
  int node = bb * BK + slot;
  if (node >= N) return;
  int s0 = sstart[bb * BK + slot];
  int end = s0 + scnt[bb * BK + slot];

  float acc[16];
#pragma unroll
  for (int k = 0; k < 16; k++) acc[k] = 0.f;

  int e = s0 + L;
  uint4 r0 = make_uint4(0,0,0,0), r1 = r0;
  if (e < end) {
    const uint4* row = (const uint4*)(g2bf + (size_t)srt[e] * H1);
    r0 = row[0]; r1 = row[1];
  }
  while (e < end) {
    int en = e + 4;
    uint4 n0 = make_uint4(0,0,0,0), n1 = n0;
    if (en < end) {
      const uint4* row = (const uint4*)(g2bf + (size_t)srt[en] * H1);
      n0 = row[0]; n1 = row[1];
    }
    acc[0]+=lo16(r0.x); acc[1]+=hi16(r0.x); acc[2]+=lo16(r0.y); acc[3]+=hi16(r0.y);
    acc[4]+=lo16(r0.z); acc[5]+=hi16(r0.z); acc[6]+=lo16(r0.w); acc[7]+=hi16(r0.w);
    acc[8]+=lo16(r1.x); acc[9]+=hi16(r1.x); acc[10]+=lo16(r1.y); acc[11]+=hi16(r1.y);
    acc[12]+=lo16(r1.z); acc[13]+=hi16(r1.z); acc[14]+=lo16(r1.w); acc[15]+=hi16(r1.w);
    r0 = n0; r1 = n1; e = en;
  }

  float r8[8];
#pragma unroll
  for (int k = 0; k < 8; k++) {
    float a = acc[k]     + __shfl_xor(acc[k],     1, 64);
    float b = acc[8 + k] + __shfl_xor(acc[8 + k], 1, 64);
    r8[k] = (L & 1) ? b : a;
  }
  float r4[4];
#pragma unroll
  for (int k = 0; k < 4; k++) {
    float a = r4[k] = r8[k] + __shfl_xor(r8[k], 2, 64);
    float b = r8[4 + k] + __shfl_xor(r8[4 + k], 2, 64);
    r4[k] = (L & 2) ? b : a;
  }
  int fb = (L & 1) * 8 + (L & 2) * 2;

  float di = dinv[node];
  uint2 sf = *(const uint2*)(g2bf + (size_t)node * H1 + fb);
  float4 o;
  o.x = di * (r4[0] + lo16(sf.x));
  o.y = di * (r4[1] + hi16(sf.x));
  o.z = di * (r4[2] + lo16(sf.y));
  o.w = di * (r4[3] + hi16(sf.y));
  *(float4*)(s2 + (size_t)node * H1 + fb) = o;
}

// ---------------- final epilogue: out = log_softmax(s2 @ W2 + b2) ----------------
__global__ __launch_bounds__(256) void k_ep2(const float* __restrict__ s2,
                                             const float* __restrict__ W2,
                                             const float* __restrict__ b2,
                                             float* __restrict__ out, int N) {
  __shared__ float w2s[H1 * C2];
  __shared__ float b2s[C2];
  int t = threadIdx.x;
  for (int i = t; i < H1 * C2; i += 256) w2s[i] = W2[i];
  if (t < C2) b2s[t] = b2[t];
  __syncthreads();

  int lane = t & 63;
  int node = (int)((blockIdx.x * (long long)blockDim.x + t) >> 6);
  if (node >= N) return;
  float sv = (lane < H1) ? s2[(size_t)node * H1 + lane] : 0.f;
  int cl = (lane < C2) ? lane : 0;
  float z = b2s[cl];
#pragma unroll
  for (int jj = 0; jj < H1; jj++) {
    float sj = __shfl(sv, jj, 64);
    z = fmaf(sj, w2s[jj * C2 + cl], z);
  }
  if (lane >= C2) z = -INFINITY;
  float m = z;
#pragma unroll
  for (int off = 32; off; off >>= 1) m = fmaxf(m, __shfl_xor(m, off, 64));
  float p = (lane < C2) ? expf(z - m) : 0.f;
  float ssum = p;
#pragma unroll
  for (int off = 32; off; off >>= 1) ssum += __shfl_xor(ssum, off, 64);
  if (lane < C2) out[(size_t)node * C2 + lane] = z - m - logf(ssum);
}

extern "C" void kernel_launch(void* const* d_in, const int* in_sizes, int n_in,
                              void* d_out, int out_size, void* d_ws, size_t ws_size,
                              hipStream_t stream) {
  const float* x  = (const float*)d_in[0];
  const int*   ei = (const int*)d_in[1];
  const float* W1 = (const float*)d_in[2];
  const float* b1 = (const float*)d_in[3];
  const float* W2 = (const float*)d_in[4];
  const float* b2 = (const float*)d_in[5];
  float* out = (float*)d_out;

  int N = in_sizes[0] / F_IN;
  int E = in_sizes[1] / 2;
  const int* src = ei;
  const int* dst = ei + E;
  int NB = (N + BK - 1) / BK;     // 1563 for N=100000 (<= NBMAX)
  int epb = (E + G - 1) / G;      // edges per chunk group

  char* w = (char*)d_ws;
  size_t off = 0;
  auto alloc = [&](size_t bytes) { char* p = w + off; off = (off + bytes + 255) & ~(size_t)255; return p; };
  int*   cnt    = (int*)alloc((size_t)G * NB * 4);
  int*   tot    = (int*)alloc((size_t)NB * 4);
  int*   bstart = (int*)alloc((size_t)(NB + 1) * 4);
  float* dinv   = (float*)alloc((size_t)N * 4);
  unsigned* ebuf = (unsigned*)alloc(((size_t)E + (size_t)NB * TPAD) * 4);
  int*   srt    = (int*)alloc(((size_t)E + (size_t)NB * TPAD) * 4);
  int*   sstart = (int*)alloc((size_t)NB * BK * 4);
  int*   scnt   = (int*)alloc((size_t)NB * BK * 4);
  unsigned short* g1bf = (unsigned short*)alloc((size_t)N * H1 * 2);
  unsigned short* g2bf = (unsigned short*)alloc((size_t)N * H1 * 2);
  float* s2 = (float*)cnt;  // alias: cnt dead after k_fill; N*16*4 <= G*NB*4

  k_count   <<<G, 256, 0, stream>>>(dst, cnt, E, NB, epb);
  k_scan_col<<<NB, G, 0, stream>>>(cnt, tot, NB);
  k_scan_tot<<<1, 512, 0, stream>>>(tot, bstart, NB);
  k_fill    <<<G, 256, 0, stream>>>(src, dst, cnt, bstart, ebuf, E, NB, epb);
  k_sort    <<<NB, 256, 0, stream>>>(ebuf, bstart, tot, srt, sstart, scnt, dinv, N);
  k_gemm1   <<<1024, 256, 0, stream>>>(x, W1, dinv, g1bf, N);
  k_agg1    <<<NB, 256, 0, stream>>>(srt, sstart, scnt, g1bf, dinv, b1, g2bf, N);
  k_agg2    <<<NB, 256, 0, stream>>>(srt, sstart, scnt, g2bf, dinv, s2, N);
  k_ep2     <<<(N * 64 + 255) / 256, 256, 0, stream>>>(s2, W2, b2, out, N);
}

// Round 9
// 254.289 us; speedup vs baseline: 3.5405x; 1.2123x over previous
//
#include <hip/hip_runtime.h>
#include <hip/hip_bf16.h>
#include <math.h>

#define F_IN 512
#define H1   16
#define C2   40
#define BKL  6                 // log2(nodes per bucket)
#define BK   (1 << BKL)        // 64 nodes per bucket
#define NBMAX 2048
#define G    256               // edge-chunk groups for count/fill
#define SEG  8                 // scan segments
#define SEGLEN 32              // G / SEG
#define TPAD 64                // bucket edge-count padding (alignment only)

__device__ __forceinline__ float bf2f(unsigned short u) {
  union { unsigned int i; float f; } v; v.i = ((unsigned int)u) << 16; return v.f;
}
__device__ __forceinline__ unsigned short f2bf(float f) {
  __hip_bfloat16 b = __float2bfloat16(f);  // RNE
  return *reinterpret_cast<unsigned short*>(&b);
}
__device__ __forceinline__ float lo16(unsigned u) { return bf2f((unsigned short)(u & 0xffffu)); }
__device__ __forceinline__ float hi16(unsigned u) { return bf2f((unsigned short)(u >> 16)); }

// ---------------- phase 1: per-chunk bucket histogram (LDS atomics only) ----------------
__global__ __launch_bounds__(1024) void k_count(const int* __restrict__ dst,
                                                int* __restrict__ cnt,
                                                int E, int NB, int epb) {
  __shared__ int h[NBMAX];
  int g = blockIdx.x, t = threadIdx.x;
  for (int i = t; i < NB; i += 1024) h[i] = 0;
  __syncthreads();
  int e0 = g * epb, e1 = min(e0 + epb, E);
  for (int e = e0 + t; e < e1; e += 1024) atomicAdd(&h[dst[e] >> BKL], 1);
  __syncthreads();
  for (int i = t; i < NB; i += 1024) cnt[g * NB + i] = h[i];
}

// ---------------- phase 2a: segmented scan over g, wave per (segment, 16 buckets) ----------------
// Coalesced row loads; shuffle-scan across the 4 g's per wave-tile; no barriers.
// In-place: cnt[g][b] becomes exclusive-prefix-within-segment; segtot[s][b] = segment sum.
__global__ __launch_bounds__(256) void k_scan_seg(int* __restrict__ cnt,
                                                  int* __restrict__ segtot,
                                                  int NB, int QB) {
  int task = blockIdx.x * 4 + (threadIdx.x >> 6);
  int lane = threadIdx.x & 63;
  if (task >= SEG * QB) return;
  int s = task / QB, q = task - s * QB;
  int gs = lane >> 4, bs = lane & 15;
  int b = q * 16 + bs;
  bool ok = b < NB;
  int run = 0;
  int gbase = s * SEGLEN;
  for (int it = 0; it < SEGLEN; it += 4) {
    int g = gbase + it + gs;
    int v = ok ? cnt[g * NB + b] : 0;
    int incl = v;
    int n1 = __shfl_up(incl, 16, 64); if (lane >= 16) incl += n1;
    int n2 = __shfl_up(incl, 32, 64); if (lane >= 32) incl += n2;
    int ttot = __shfl(incl, 48 + bs, 64);
    if (ok) cnt[g * NB + b] = run + incl - v;
    run += ttot;
  }
  if (gs == 0 && ok) segtot[s * NB + b] = run;
}

// ---------------- phase 2b: per-bucket exclusive scan of segment totals (in place) + tot ----------------
__global__ __launch_bounds__(256) void k_segscan(int* __restrict__ segtot,
                                                 int* __restrict__ tot, int NB) {
  int b = blockIdx.x * 256 + threadIdx.x;
  if (b >= NB) return;
  int run = 0;
#pragma unroll
  for (int s = 0; s < SEG; s++) {
    int v = segtot[s * NB + b];
    segtot[s * NB + b] = run;   // exclusive base for this segment
    run += v;
  }
  tot[b] = run;
}

// ---------------- phase 2c: exclusive scan of (aligned) bucket totals ----------------
__global__ __launch_bounds__(512) void k_scan_tot(const int* __restrict__ tot,
                                                  int* bstart, int NB) {
  __shared__ int lds[512];
  int t = threadIdx.x;
  int b0 = t * 4;
  int v[4];
  int s = 0;
#pragma unroll
  for (int k = 0; k < 4; k++) {
    int tv = (b0 + k < NB) ? tot[b0 + k] : 0;
    v[k] = (tv + TPAD - 1) & ~(TPAD - 1);   // pad to multiple of TPAD (alignment)
    s += v[k];
  }
  lds[t] = s;
  __syncthreads();
  for (int off = 1; off < 512; off <<= 1) {
    int add = (t >= off) ? lds[t - off] : 0;
    __syncthreads();
    lds[t] += add;
    __syncthreads();
  }
  int excl = lds[t] - s;
#pragma unroll
  for (int k = 0; k < 4; k++) {
    if (b0 + k < NB) bstart[b0 + k] = excl;
    excl += v[k];
  }
  if (t == 511) bstart[NB] = excl;
}

// ---------------- phase 3: fill (LDS cursors, private sub-ranges, no global atomics) ----------------
__global__ __launch_bounds__(1024) void k_fill(const int* __restrict__ src,
                                               const int* __restrict__ dst,
                                               const int* __restrict__ cnt,
                                               const int* __restrict__ segtot,
                                               const int* __restrict__ bstart,
                                               unsigned* __restrict__ ebuf,
                                               int E, int NB, int epb) {
  __shared__ int cur[NBMAX];
  int g = blockIdx.x, t = threadIdx.x;
  int s = g / SEGLEN;
  for (int i = t; i < NB; i += 1024)
    cur[i] = bstart[i] + segtot[s * NB + i] + cnt[g * NB + i];
  __syncthreads();
  int e0 = g * epb, e1 = min(e0 + epb, E);
  for (int e = e0 + t; e < e1; e += 1024) {
    int d = dst[e];
    int pos = atomicAdd(&cur[d >> BKL], 1);
    ebuf[pos] = ((unsigned)src[e] << BKL) | (unsigned)(d & (BK - 1));
  }
}

// ---------------- phase 4: per-bucket counting sort by dst slot ----------------
__global__ __launch_bounds__(256) void k_sort(const unsigned* __restrict__ ebuf,
                                              const int* __restrict__ bstart,
                                              const int* __restrict__ tot,
                                              int* __restrict__ srt,
                                              int* __restrict__ sstart,
                                              int* __restrict__ scnt,
                                              float* __restrict__ dinv, int N) {
  __shared__ int h[4][BK];
  __shared__ int cur[4][BK];
  __shared__ int stmp[BK];
  int b = blockIdx.x, t = threadIdx.x;
  int w = t >> 6;
  if (t < BK) { h[0][t] = 0; h[1][t] = 0; h[2][t] = 0; h[3][t] = 0; }
  __syncthreads();
  int e0 = bstart[b], e1 = e0 + tot[b];
  for (int e = e0 + t; e < e1; e += 256)
    atomicAdd(&h[w][ebuf[e] & (BK - 1)], 1);
  __syncthreads();
  if (t < BK) stmp[t] = h[0][t] + h[1][t] + h[2][t] + h[3][t];
  __syncthreads();
  if (t < BK) {  // wave 0 exactly: shuffle inclusive scan over 64 slots
    int v = stmp[t];
    int inc = v;
#pragma unroll
    for (int off = 1; off < 64; off <<= 1) {
      int n = __shfl_up(inc, off, 64);
      if (t >= off) inc += n;
    }
    int excl = inc - v;
    scnt[b * BK + t] = v;
    sstart[b * BK + t] = e0 + excl;
    int node = b * BK + t;
    if (node < N) dinv[node] = rsqrtf((float)(v + 1));
    int base = excl;
    cur[0][t] = base; base += h[0][t];
    cur[1][t] = base; base += h[1][t];
    cur[2][t] = base; base += h[2][t];
    cur[3][t] = base;
  }
  __syncthreads();
  for (int e = e0 + t; e < e1; e += 256) {
    unsigned p = ebuf[e];
    int pos = atomicAdd(&cur[w][p & (BK - 1)], 1);
    srt[e0 + pos] = (int)(p >> BKL);
  }
}

// ---------------- g1 = bf16( (x @ W1) * dinv[row] ), 2 rows/wave ----------------
__global__ __launch_bounds__(256, 2) void k_gemm1(const float* __restrict__ x,
                                                  const float* __restrict__ W1,
                                                  const float* __restrict__ dinv,
                                                  unsigned short* __restrict__ g1bf, int N) {
  int lane = threadIdx.x & 63;
  int wid = (int)((blockIdx.x * (long long)blockDim.x + threadIdx.x) >> 6);
  int nw = (gridDim.x * blockDim.x) >> 6;

  float wr[128];
#pragma unroll
  for (int j = 0; j < 8; j++) {
    const float* wrow = &W1[(lane * 8 + j) * H1];
    float4 w0 = *(const float4*)&wrow[0];
    float4 w1 = *(const float4*)&wrow[4];
    float4 w2 = *(const float4*)&wrow[8];
    float4 w3 = *(const float4*)&wrow[12];
    wr[j*16+ 0]=w0.x; wr[j*16+ 1]=w0.y; wr[j*16+ 2]=w0.z; wr[j*16+ 3]=w0.w;
    wr[j*16+ 4]=w1.x; wr[j*16+ 5]=w1.y; wr[j*16+ 6]=w1.z; wr[j*16+ 7]=w1.w;
    wr[j*16+ 8]=w2.x; wr[j*16+ 9]=w2.y; wr[j*16+10]=w2.z; wr[j*16+11]=w2.w;
    wr[j*16+12]=w3.x; wr[j*16+13]=w3.y; wr[j*16+14]=w3.z; wr[j*16+15]=w3.w;
  }

  int row = wid * 2;
  int step = nw * 2;
  float4 A0 = make_float4(0,0,0,0), A1 = A0, B0 = A0, B1 = A0;
  if (row < N) {
    const float4* xr = (const float4*)(x + (size_t)row * F_IN);
    A0 = xr[lane * 2]; A1 = xr[lane * 2 + 1];
    if (row + 1 < N) {
      const float4* xr2 = (const float4*)(x + (size_t)(row + 1) * F_IN);
      B0 = xr2[lane * 2]; B1 = xr2[lane * 2 + 1];
    }
  }
  while (row < N) {
    int nrow = row + step;
    float4 nA0 = make_float4(0,0,0,0), nA1 = nA0, nB0 = nA0, nB1 = nA0;
    if (nrow < N) {
      const float4* xr = (const float4*)(x + (size_t)nrow * F_IN);
      nA0 = xr[lane * 2]; nA1 = xr[lane * 2 + 1];
      if (nrow + 1 < N) {
        const float4* xr2 = (const float4*)(x + (size_t)(nrow + 1) * F_IN);
        nB0 = xr2[lane * 2]; nB1 = xr2[lane * 2 + 1];
      }
    }
    float xa[8] = {A0.x, A0.y, A0.z, A0.w, A1.x, A1.y, A1.z, A1.w};
    float xb[8] = {B0.x, B0.y, B0.z, B0.w, B1.x, B1.y, B1.z, B1.w};
    float accA[16], accB[16];
#pragma unroll
    for (int c = 0; c < 16; c++) { accA[c] = 0.f; accB[c] = 0.f; }
#pragma unroll
    for (int j = 0; j < 8; j++)
#pragma unroll
      for (int c = 0; c < 16; c++) {
        accA[c] = fmaf(xa[j], wr[j * 16 + c], accA[c]);
        accB[c] = fmaf(xb[j], wr[j * 16 + c], accB[c]);
      }

    float a8[8], b8[8];
#pragma unroll
    for (int i = 0; i < 8; i++) {
      float t0 = accA[2*i]   + __shfl_xor(accA[2*i],   1, 64);
      float t1 = accA[2*i+1] + __shfl_xor(accA[2*i+1], 1, 64);
      a8[i] = (lane & 1) ? t1 : t0;
      float s0 = accB[2*i]   + __shfl_xor(accB[2*i],   1, 64);
      float s1 = accB[2*i+1] + __shfl_xor(accB[2*i+1], 1, 64);
      b8[i] = (lane & 1) ? s1 : s0;
    }
    float a4[4], b4[4];
#pragma unroll
    for (int i = 0; i < 4; i++) {
      float t0 = a8[2*i]   + __shfl_xor(a8[2*i],   2, 64);
      float t1 = a8[2*i+1] + __shfl_xor(a8[2*i+1], 2, 64);
      a4[i] = ((lane >> 1) & 1) ? t1 : t0;
      float s0 = b8[2*i]   + __shfl_xor(b8[2*i],   2, 64);
      float s1 = b8[2*i+1] + __shfl_xor(b8[2*i+1], 2, 64);
      b4[i] = ((lane >> 1) & 1) ? s1 : s0;
    }
    float a2[2], b2v[2];
#pragma unroll
    for (int i = 0; i < 2; i++) {
      float t0 = a4[2*i]   + __shfl_xor(a4[2*i],   4, 64);
      float t1 = a4[2*i+1] + __shfl_xor(a4[2*i+1], 4, 64);
      a2[i] = ((lane >> 2) & 1) ? t1 : t0;
      float s0 = b4[2*i]   + __shfl_xor(b4[2*i],   4, 64);
      float s1 = b4[2*i+1] + __shfl_xor(b4[2*i+1], 4, 64);
      b2v[i] = ((lane >> 2) & 1) ? s1 : s0;
    }
    float ta0 = a2[0] + __shfl_xor(a2[0], 8, 64);
    float ta1 = a2[1] + __shfl_xor(a2[1], 8, 64);
    float va = ((lane >> 3) & 1) ? ta1 : ta0;
    float tb0 = b2v[0] + __shfl_xor(b2v[0], 8, 64);
    float tb1 = b2v[1] + __shfl_xor(b2v[1], 8, 64);
    float vb = ((lane >> 3) & 1) ? tb1 : tb0;
    va += __shfl_xor(va, 16, 64); va += __shfl_xor(va, 32, 64);
    vb += __shfl_xor(vb, 16, 64); vb += __shfl_xor(vb, 32, 64);

    if (lane < 16) {
      g1bf[(size_t)row * H1 + lane] = f2bf(va * dinv[row]);
      if (row + 1 < N) g1bf[(size_t)(row + 1) * H1 + lane] = f2bf(vb * dinv[row + 1]);
    }
    row = nrow; A0 = nA0; A1 = nA1; B0 = nB0; B1 = nB1;
  }
}

// ---------------- layer-1 aggregate: LDS-free, 8 lanes/node, register acc ----------------
__global__ __launch_bounds__(256) void k_agg1(const int* __restrict__ srt,
                                              const int* __restrict__ sstart,
                                              const int* __restrict__ scnt,
                                              const unsigned short* __restrict__ g1bf,
                                              const float* __restrict__ dinv,
                                              const float* __restrict__ b1,
                                              unsigned short* __restrict__ g2bf, int N) {
  int t = threadIdx.x;
  int bb = blockIdx.x >> 1, half = blockIdx.x & 1;
  int slot = half * 32 + (t >> 3), L = t & 7;
  int node = bb * BK + slot;
  if (node >= N) return;  // no __syncthreads in this kernel
  int idx = bb * BK + slot;
  int s0 = sstart[idx];
  int end = s0 + scnt[idx];

  float acc[16];
#pragma unroll
  for (int k = 0; k < 16; k++) acc[k] = 0.f;

  int e = s0 + L;
  uint4 r0 = make_uint4(0,0,0,0), r1 = r0;
  if (e < end) {
    const uint4* row = (const uint4*)(g1bf + (size_t)srt[e] * H1);
    r0 = row[0]; r1 = row[1];
  }
  while (e < end) {
    int en = e + 8;
    uint4 n0 = make_uint4(0,0,0,0), n1 = n0;
    if (en < end) {
      const uint4* row = (const uint4*)(g1bf + (size_t)srt[en] * H1);
      n0 = row[0]; n1 = row[1];
    }
    acc[0]+=lo16(r0.x); acc[1]+=hi16(r0.x); acc[2]+=lo16(r0.y); acc[3]+=hi16(r0.y);
    acc[4]+=lo16(r0.z); acc[5]+=hi16(r0.z); acc[6]+=lo16(r0.w); acc[7]+=hi16(r0.w);
    acc[8]+=lo16(r1.x); acc[9]+=hi16(r1.x); acc[10]+=lo16(r1.y); acc[11]+=hi16(r1.y);
    acc[12]+=lo16(r1.z); acc[13]+=hi16(r1.z); acc[14]+=lo16(r1.w); acc[15]+=hi16(r1.w);
    r0 = n0; r1 = n1; e = en;
  }

  // 3-round reduce-scatter across the 8-lane group: lane keeps 2 features
  float r8[8];
#pragma unroll
  for (int k = 0; k < 8; k++) {
    float a = acc[k]     + __shfl_xor(acc[k],     1, 64);
    float b = acc[8 + k] + __shfl_xor(acc[8 + k], 1, 64);
    r8[k] = (L & 1) ? b : a;
  }
  float r4[4];
#pragma unroll
  for (int k = 0; k < 4; k++) {
    float a = r8[k]     + __shfl_xor(r8[k],     2, 64);
    float b = r8[4 + k] + __shfl_xor(r8[4 + k], 2, 64);
    r4[k] = (L & 2) ? b : a;
  }
  float r2[2];
#pragma unroll
  for (int k = 0; k < 2; k++) {
    float a = r4[k]     + __shfl_xor(r4[k],     4, 64);
    float b = r4[2 + k] + __shfl_xor(r4[2 + k], 4, 64);
    r2[k] = (L & 4) ? b : a;
  }
  int fb = ((L & 1) << 3) | ((L & 2) << 1) | ((L & 4) >> 1);  // even, bijective

  float di = dinv[node];
  unsigned sf = *(const unsigned*)(g1bf + (size_t)node * H1 + fb);
  float v0 = fmaxf(di * (r2[0] + lo16(sf)) + b1[fb],     0.f) * di;
  float v1 = fmaxf(di * (r2[1] + hi16(sf)) + b1[fb + 1], 0.f) * di;
  *(unsigned*)(g2bf + (size_t)node * H1 + fb) = (unsigned)f2bf(v0) | ((unsigned)f2bf(v1) << 16);
}

// ---------------- layer-2 aggregate: LDS-free, 8 lanes/node -> s2 fp32 ----------------
__global__ __launch_bounds__(256) void k_agg2(const int* __restrict__ srt,
                                              const int* __restrict__ sstart,
                                              const int* __restrict__ scnt,
                                              const unsigned short* __restrict__ g2bf,
                                              const float* __restrict__ dinv,
                                              float* __restrict__ s2, int N) {
  int t = threadIdx.x;
  int bb = blockIdx.x >> 1, half = blockIdx.x & 1;
  int slot = half * 32 + (t >> 3), L = t & 7;
  int node = bb * BK + slot;
  if (node >= N) return;
  int idx = bb * BK + slot;
  int s0 = sstart[idx];
  int end = s0 + scnt[idx];

  float acc[16];
#pragma unroll
  for (int k = 0; k < 16; k++) acc[k] = 0.f;

  int e = s0 + L;
  uint4 r0 = make_uint4(0,0,0,0), r1 = r0;
  if (e < end) {
    const uint4* row = (const uint4*)(g2bf + (size_t)srt[e] * H1);
    r0 = row[0]; r1 = row[1];
  }
  while (e < end) {
    int en = e + 8;
    uint4 n0 = make_uint4(0,0,0,0), n1 = n0;
    if (en < end) {
      const uint4* row = (const uint4*)(g2bf + (size_t)srt[en] * H1);
      n0 = row[0]; n1 = row[1];
    }
    acc[0]+=lo16(r0.x); acc[1]+=hi16(r0.x); acc[2]+=lo16(r0.y); acc[3]+=hi16(r0.y);
    acc[4]+=lo16(r0.z); acc[5]+=hi16(r0.z); acc[6]+=lo16(r0.w); acc[7]+=hi16(r0.w);
    acc[8]+=lo16(r1.x); acc[9]+=hi16(r1.x); acc[10]+=lo16(r1.y); acc[11]+=hi16(r1.y);
    acc[12]+=lo16(r1.z); acc[13]+=hi16(r1.z); acc[14]+=lo16(r1.w); acc[15]+=hi16(r1.w);
    r0 = n0; r1 = n1; e = en;
  }

  float r8[8];
#pragma unroll
  for (int k = 0; k < 8; k++) {
    float a = acc[k]     + __shfl_xor(acc[k],     1, 64);
    float b = acc[8 + k] + __shfl_xor(acc[8 + k], 1, 64);
    r8[k] = (L & 1) ? b : a;
  }
  float r4[4];
#pragma unroll
  for (int k = 0; k < 4; k++) {
    float a = r8[k]     + __shfl_xor(r8[k],     2, 64);
    float b = r8[4 + k] + __shfl_xor(r8[4 + k], 2, 64);
    r4[k] = (L & 2) ? b : a;
  }
  float r2[2];
#pragma unroll
  for (int k = 0; k < 2; k++) {
    float a = r4[k]     + __shfl_xor(r4[k],     4, 64);
    float b = r4[2 + k] + __shfl_xor(r4[2 + k], 4, 64);
    r2[k] = (L & 4) ? b : a;
  }
  int fb = ((L & 1) << 3) | ((L & 2) << 1) | ((L & 4) >> 1);

  float di = dinv[node];
  unsigned sf = *(const unsigned*)(g2bf + (size_t)node * H1 + fb);
  float2 o;
  o.x = di * (r2[0] + lo16(sf));
  o.y = di * (r2[1] + hi16(sf));
  *(float2*)(s2 + (size_t)node * H1 + fb) = o;
}

// ---------------- final epilogue: out = log_softmax(s2 @ W2 + b2) ----------------
__global__ __launch_bounds__(256) void k_ep2(const float* __restrict__ s2,
                                             const float* __restrict__ W2,
                                             const float* __restrict__ b2,
                                             float* __restrict__ out, int N) {
  __shared__ float w2s[H1 * C2];
  __shared__ float b2s[C2];
  int t = threadIdx.x;
  for (int i = t; i < H1 * C2; i += 256) w2s[i] = W2[i];
  if (t < C2) b2s[t] = b2[t];
  __syncthreads();

  int lane = t & 63;
  int node = (int)((blockIdx.x * (long long)blockDim.x + t) >> 6);
  if (node >= N) return;
  float sv = (lane < H1) ? s2[(size_t)node * H1 + lane] : 0.f;
  int cl = (lane < C2) ? lane : 0;
  float z = b2s[cl];
#pragma unroll
  for (int jj = 0; jj < H1; jj++) {
    float sj = __shfl(sv, jj, 64);
    z = fmaf(sj, w2s[jj * C2 + cl], z);
  }
  if (lane >= C2) z = -INFINITY;
  float m = z;
#pragma unroll
  for (int off = 32; off; off >>= 1) m = fmaxf(m, __shfl_xor(m, off, 64));
  float p = (lane < C2) ? expf(z - m) : 0.f;
  float ssum = p;
#pragma unroll
  for (int off = 32; off; off >>= 1) ssum += __shfl_xor(ssum, off, 64);
  if (lane < C2) out[(size_t)node * C2 + lane] = z - m - logf(ssum);
}

extern "C" void kernel_launch(void* const* d_in, const int* in_sizes, int n_in,
                              void* d_out, int out_size, void* d_ws, size_t ws_size,
                              hipStream_t stream) {
  const float* x  = (const float*)d_in[0];
  const int*   ei = (const int*)d_in[1];
  const float* W1 = (const float*)d_in[2];
  const float* b1 = (const float*)d_in[3];
  const float* W2 = (const float*)d_in[4];
  const float* b2 = (const float*)d_in[5];
  float* out = (float*)d_out;

  int N = in_sizes[0] / F_IN;
  int E = in_sizes[1] / 2;
  const int* src = ei;
  const int* dst = ei + E;
  int NB = (N + BK - 1) / BK;     // 1563 for N=100000 (<= NBMAX)
  int QB = (NB + 15) / 16;        // bucket-groups of 16 for the segmented scan
  int epb = (E + G - 1) / G;      // edges per chunk group

  char* w = (char*)d_ws;
  size_t off = 0;
  auto alloc = [&](size_t bytes) { char* p = w + off; off = (off + bytes + 255) & ~(size_t)255; return p; };
  int*   cnt    = (int*)alloc((size_t)G * NB * 4);
  int*   segtot = (int*)alloc((size_t)SEG * NB * 4);
  int*   tot    = (int*)alloc((size_t)NB * 4);
  int*   bstart = (int*)alloc((size_t)(NB + 1) * 4);
  float* dinv   = (float*)alloc((size_t)N * 4);
  unsigned* ebuf = (unsigned*)alloc(((size_t)E + (size_t)NB * TPAD) * 4);
  int*   srt    = (int*)alloc(((size_t)E + (size_t)NB * TPAD) * 4);
  int*   sstart = (int*)alloc((size_t)NB * BK * 4);
  int*   scnt   = (int*)alloc((size_t)NB * BK * 4);
  unsigned short* g1bf = (unsigned short*)alloc((size_t)N * H1 * 2);
  unsigned short* g2bf = (unsigned short*)alloc((size_t)N * H1 * 2);
  float* s2     = (float*)alloc((size_t)N * H1 * 4);

  k_count   <<<G, 1024, 0, stream>>>(dst, cnt, E, NB, epb);
  k_scan_seg<<<(SEG * QB + 3) / 4, 256, 0, stream>>>(cnt, segtot, NB, QB);
  k_segscan <<<(NB + 255) / 256, 256, 0, stream>>>(segtot, tot, NB);
  k_scan_tot<<<1, 512, 0, stream>>>(tot, bstart, NB);
  k_fill    <<<G, 1024, 0, stream>>>(src, dst, cnt, segtot, bstart, ebuf, E, NB, epb);
  k_sort    <<<NB, 256, 0, stream>>>(ebuf, bstart, tot, srt, sstart, scnt, dinv, N);
  k_gemm1   <<<1024, 256, 0, stream>>>(x, W1, dinv, g1bf, N);
  k_agg1    <<<NB * 2, 256, 0, stream>>>(srt, sstart, scnt, g1bf, dinv, b1, g2bf, N);
  k_agg2    <<<NB * 2, 256, 0, stream>>>(srt, sstart, scnt, g2bf, dinv, s2, N);
  k_ep2     <<<(N * 64 + 255) / 256, 256, 0, stream>>>(s2, W2, b2, out, N);
}